// Round 4
// baseline (271.060 us; speedup 1.0000x reference)
//
#include <hip/hip_runtime.h>

static constexpr int kDim   = 256;
static constexpr int kInner = 64;
static constexpr int kNH    = 8;
static constexpr int kHD    = 8;
static constexpr int kB     = 2;
static constexpr int kP     = 2304;   // 48*48
static constexpr float kScale = 0.35355339059327373f; // 8^-0.5
static constexpr float kEps   = 1e-6f;

// ---------------- LayerNorm over channels (C=256), both images in one launch.
// Block 256 = 16 positions x 16 channel-groups (16 ch each). grid (288, 2).
// In-place safe (each thread rewrites exactly what it read, values kept in regs).
__global__ __launch_bounds__(256) void ln2_kernel(
    const float* __restrict__ x0, const float* __restrict__ w0,
    const float* __restrict__ b0, float* __restrict__ o0,
    const float* __restrict__ x1, const float* __restrict__ w1,
    const float* __restrict__ b1, float* __restrict__ o1)
{
    __shared__ float sb[16][16];
    __shared__ float ssb[16][16];
    const float* x = blockIdx.y ? x1 : x0;
    const float* w = blockIdx.y ? w1 : w0;
    const float* b = blockIdx.y ? b1 : b0;
    float*       o = blockIdx.y ? o1 : o0;
    const int pos = threadIdx.x & 15;
    const int grp = threadIdx.x >> 4;
    const int idx = blockIdx.x * 16 + pos;        // global (b,p) in 0..4607
    const int bb  = idx / kP;
    const int p   = idx - bb * kP;
    const size_t base = (size_t)bb * kDim * kP + p;
    const int c0 = grp * 16;

    float v[16];
    float s = 0.f, ss = 0.f;
    #pragma unroll
    for (int j = 0; j < 16; ++j) {
        v[j] = x[base + (size_t)(c0 + j) * kP];
        s += v[j]; ss += v[j] * v[j];
    }
    sb[grp][pos] = s; ssb[grp][pos] = ss;
    __syncthreads();
    float st = 0.f, sst = 0.f;
    #pragma unroll
    for (int g = 0; g < 16; ++g) { st += sb[g][pos]; sst += ssb[g][pos]; }
    const float mean = st * (1.f / kDim);
    const float rstd = rsqrtf(sst * (1.f / kDim) - mean * mean + kEps);
    #pragma unroll
    for (int j = 0; j < 16; ++j)
        o[base + (size_t)(c0 + j) * kP] = (v[j] - mean) * rstd * w[c0 + j] + b[c0 + j];
}

// ---------------- fused q/kv projections (C=256), 8 outputs per thread.
// Weights read directly via wave-uniform float4 loads (s_load promotion path).
// grid (9, 24, 4): y = o-tile (0..7 -> q, 8..23 -> kv), z = input*2 + batch.
__global__ __launch_bounds__(256) void qkv_conv(
    const float* __restrict__ n_rgb, const float* __restrict__ n_ir,
    const float* __restrict__ qr_w, const float* __restrict__ qr_b,
    const float* __restrict__ kvr_w, const float* __restrict__ kvr_b,
    const float* __restrict__ qi_w, const float* __restrict__ qi_b,
    const float* __restrict__ kvi_w, const float* __restrict__ kvi_b,
    float* __restrict__ q_r, float* __restrict__ kv_r,
    float* __restrict__ q_i, float* __restrict__ kv_i)
{
    const int inp  = blockIdx.z >> 1, bb = blockIdx.z & 1;
    const int tile = blockIdx.y;
    const float* in = inp ? n_ir : n_rgb;
    const float* w; const float* bias; float* out; int O, ot;
    if (tile < 8) {
        w = inp ? qi_w : qr_w;   bias = inp ? qi_b : qr_b;
        out = inp ? q_i : q_r;   O = kInner;     ot = tile * 8;
    } else {
        w = inp ? kvi_w : kvr_w; bias = inp ? kvi_b : kvr_b;
        out = inp ? kv_i : kv_r; O = 2 * kInner; ot = (tile - 8) * 8;
    }
    const int p = blockIdx.x * 256 + threadIdx.x;
    const float* ip = in + (size_t)bb * kDim * kP + p;
    float acc[8];
    #pragma unroll
    for (int r = 0; r < 8; ++r) acc[r] = bias[ot + r];
    #pragma unroll 2
    for (int c = 0; c < kDim; c += 4) {
        float v[4];
        #pragma unroll
        for (int j = 0; j < 4; ++j) v[j] = ip[(size_t)(c + j) * kP];
        #pragma unroll
        for (int r = 0; r < 8; ++r) {
            const float4 w4 = *(const float4*)(w + (size_t)(ot + r) * kDim + c);
            const float* ww = (const float*)&w4;
            #pragma unroll
            for (int j = 0; j < 4; ++j) acc[r] = fmaf(ww[j], v[j], acc[r]);
        }
    }
    float* op = out + ((size_t)bb * O + ot) * kP + p;
    #pragma unroll
    for (int r = 0; r < 8; ++r) op[(size_t)r * kP] = acc[r];
}

// ---------------- attention, single-pass (no max-subtract: |scores| ~ 0.1),
// split-K x NS. K/V read via wave-uniform float4 loads (no LDS).
// grid (9, 16, 2*NS): z = stream*NS + chunk. Writes (sum, o[8]) partials.
template <int NS>
__global__ __launch_bounds__(256) void attn_part(
    const float* __restrict__ q0, const float* __restrict__ kv0,
    const float* __restrict__ q1, const float* __restrict__ kv1,
    float* __restrict__ part)      // [2*16*NS][9][2304]
{
    constexpr int CH = kP / NS;
    const int stream = blockIdx.z / NS, chunk = blockIdx.z % NS;
    const float* q  = stream ? q1  : q0;
    const float* kv = stream ? kv1 : kv0;
    const int bh = blockIdx.y;
    const int bb = bh >> 3, h = bh & 7;
    const int p  = blockIdx.x * 256 + threadIdx.x;

    const float* qb = q  + ((size_t)bb * kInner + h * kHD) * kP + p;
    const float* kb = kv + ((size_t)bb * 2 * kInner + h * kHD) * kP + chunk * CH;
    const float* vb = kb + (size_t)kInner * kP;

    float qv[kHD];
    #pragma unroll
    for (int d = 0; d < kHD; ++d) qv[d] = qb[(size_t)d * kP] * kScale;

    float sum = 0.f;
    float ov[kHD];
    #pragma unroll
    for (int d = 0; d < kHD; ++d) ov[d] = 0.f;

    #pragma unroll 2
    for (int m0 = 0; m0 < CH; m0 += 4) {
        float4 k4[kHD], v4[kHD];
        #pragma unroll
        for (int d = 0; d < kHD; ++d) {
            k4[d] = *(const float4*)(kb + (size_t)d * kP + m0);
            v4[d] = *(const float4*)(vb + (size_t)d * kP + m0);
        }
        float s[4] = {0.f, 0.f, 0.f, 0.f};
        #pragma unroll
        for (int d = 0; d < kHD; ++d) {
            const float* kk = (const float*)&k4[d];
            #pragma unroll
            for (int j = 0; j < 4; ++j) s[j] = fmaf(qv[d], kk[j], s[j]);
        }
        float e[4];
        #pragma unroll
        for (int j = 0; j < 4; ++j) { e[j] = __expf(s[j]); }
        sum += (e[0] + e[1]) + (e[2] + e[3]);
        #pragma unroll
        for (int d = 0; d < kHD; ++d) {
            const float* vv = (const float*)&v4[d];
            ov[d] = fmaf(e[0], vv[0], fmaf(e[1], vv[1], fmaf(e[2], vv[2], fmaf(e[3], vv[3], ov[d]))));
        }
    }
    float* pp = part + (size_t)((stream * 16 + bh) * NS + chunk) * 9 * kP + p;
    pp[0] = sum;
    #pragma unroll
    for (int d = 0; d < kHD; ++d) pp[(size_t)(1 + d) * kP] = ov[d];
}

// ---------------- combine split-K partials. grid (9, 16, 2): z = stream.
template <int NS>
__global__ __launch_bounds__(256) void attn_combine(
    const float* __restrict__ part, float* __restrict__ a_rgb, float* __restrict__ a_ir)
{
    const int stream = blockIdx.z;
    const int bh = blockIdx.y;
    const int bb = bh >> 3, h = bh & 7;
    const int p  = blockIdx.x * 256 + threadIdx.x;
    float sum = 0.f;
    float ov[kHD];
    #pragma unroll
    for (int d = 0; d < kHD; ++d) ov[d] = 0.f;
    #pragma unroll
    for (int c = 0; c < NS; ++c) {
        const float* pp = part + (size_t)((stream * 16 + bh) * NS + c) * 9 * kP + p;
        sum += pp[0];
        #pragma unroll
        for (int d = 0; d < kHD; ++d) ov[d] += pp[(size_t)(1 + d) * kP];
    }
    const float inv = 1.f / sum;
    float* a = (stream ? a_ir : a_rgb) + ((size_t)bb * kInner + h * kHD) * kP + p;
    #pragma unroll
    for (int d = 0; d < kHD; ++d) a[(size_t)d * kP] = ov[d] * inv;
}

// ---------------- output projection (C=64 -> O=256), both streams.
// grid (9, 32, 4): z = stream*2 + batch.
__global__ __launch_bounds__(256) void proj_conv(
    const float* __restrict__ a_rgb, const float* __restrict__ a_ir,
    const float* __restrict__ pr_w, const float* __restrict__ pr_b,
    const float* __restrict__ pi_w, const float* __restrict__ pi_b,
    float* __restrict__ c_rgb, float* __restrict__ c_ir)
{
    const int stream = blockIdx.z >> 1, bb = blockIdx.z & 1;
    const int ot = blockIdx.y * 8;
    const float* in   = stream ? a_ir : a_rgb;
    const float* w    = stream ? pi_w : pr_w;
    const float* bias = stream ? pi_b : pr_b;
    float*       out  = stream ? c_ir : c_rgb;
    const int p = blockIdx.x * 256 + threadIdx.x;
    const float* ip = in + (size_t)bb * kInner * kP + p;
    float acc[8];
    #pragma unroll
    for (int r = 0; r < 8; ++r) acc[r] = bias[ot + r];
    #pragma unroll 2
    for (int c = 0; c < kInner; c += 4) {
        float v[4];
        #pragma unroll
        for (int j = 0; j < 4; ++j) v[j] = ip[(size_t)(c + j) * kP];
        #pragma unroll
        for (int r = 0; r < 8; ++r) {
            const float4 w4 = *(const float4*)(w + (size_t)(ot + r) * kInner + c);
            const float* ww = (const float*)&w4;
            #pragma unroll
            for (int j = 0; j < 4; ++j) acc[r] = fmaf(ww[j], v[j], acc[r]);
        }
    }
    float* op = out + ((size_t)bb * kDim + ot) * kP + p;
    #pragma unroll
    for (int r = 0; r < 8; ++r) op[(size_t)r * kP] = acc[r];
}

// ---------------- gate + residual (C=512 -> O=256), both streams.
// grid (9, 32, 4): z = stream*2 + batch.
__global__ __launch_bounds__(256) void gate_conv(
    const float* __restrict__ f_rgb, const float* __restrict__ f_ir,
    const float* __restrict__ c_rgb, const float* __restrict__ c_ir,
    const float* __restrict__ gr_w, const float* __restrict__ gr_b,
    const float* __restrict__ gi_w, const float* __restrict__ gi_b,
    float* __restrict__ out_rgb, float* __restrict__ out_ir)
{
    const int stream = blockIdx.z >> 1, bb = blockIdx.z & 1;
    const int ot = blockIdx.y * 8;
    const float* f    = stream ? f_ir  : f_rgb;
    const float* cr   = stream ? c_ir  : c_rgb;
    const float* w    = stream ? gi_w  : gr_w;
    const float* bias = stream ? gi_b  : gr_b;
    float*       out  = stream ? out_ir : out_rgb;
    const int p = blockIdx.x * 256 + threadIdx.x;
    const float* fb = f  + (size_t)bb * kDim * kP + p;
    const float* cb = cr + (size_t)bb * kDim * kP + p;
    float acc[8];
    #pragma unroll
    for (int r = 0; r < 8; ++r) acc[r] = bias[ot + r];
    #pragma unroll 2
    for (int c = 0; c < kDim; c += 4) {
        float v[4];
        #pragma unroll
        for (int j = 0; j < 4; ++j) v[j] = fb[(size_t)(c + j) * kP];
        #pragma unroll
        for (int r = 0; r < 8; ++r) {
            const float4 w4 = *(const float4*)(w + (size_t)(ot + r) * (2 * kDim) + c);
            const float* ww = (const float*)&w4;
            #pragma unroll
            for (int j = 0; j < 4; ++j) acc[r] = fmaf(ww[j], v[j], acc[r]);
        }
    }
    #pragma unroll 2
    for (int c = 0; c < kDim; c += 4) {
        float v[4];
        #pragma unroll
        for (int j = 0; j < 4; ++j) v[j] = cb[(size_t)(c + j) * kP];
        #pragma unroll
        for (int r = 0; r < 8; ++r) {
            const float4 w4 = *(const float4*)(w + (size_t)(ot + r) * (2 * kDim) + kDim + c);
            const float* ww = (const float*)&w4;
            #pragma unroll
            for (int j = 0; j < 4; ++j) acc[r] = fmaf(ww[j], v[j], acc[r]);
        }
    }
    float* op = out + ((size_t)bb * kDim + ot) * kP + p;
    #pragma unroll
    for (int r = 0; r < 8; ++r) {
        const float g = 1.f / (1.f + __expf(-acc[r]));
        op[(size_t)r * kP] = fb[(size_t)(ot + r) * kP] + g * cb[(size_t)(ot + r) * kP];
    }
}

extern "C" void kernel_launch(void* const* d_in, const int* in_sizes, int n_in,
                              void* d_out, int out_size, void* d_ws, size_t ws_size,
                              hipStream_t stream)
{
    const float* f_rgb  = (const float*)d_in[0];
    const float* f_ir   = (const float*)d_in[1];
    const float* nr_w   = (const float*)d_in[2];
    const float* nr_b   = (const float*)d_in[3];
    const float* ni_w   = (const float*)d_in[4];
    const float* ni_b   = (const float*)d_in[5];
    const float* qr_w   = (const float*)d_in[6];
    const float* qr_b   = (const float*)d_in[7];
    const float* kvi_w  = (const float*)d_in[8];
    const float* kvi_b  = (const float*)d_in[9];
    const float* qi_w   = (const float*)d_in[10];
    const float* qi_b   = (const float*)d_in[11];
    const float* kvr_w  = (const float*)d_in[12];
    const float* kvr_b  = (const float*)d_in[13];
    const float* pr_w   = (const float*)d_in[14];
    const float* pr_b   = (const float*)d_in[15];
    const float* pr_lnw = (const float*)d_in[16];
    const float* pr_lnb = (const float*)d_in[17];
    const float* pi_w   = (const float*)d_in[18];
    const float* pi_b   = (const float*)d_in[19];
    const float* pi_lnw = (const float*)d_in[20];
    const float* pi_lnb = (const float*)d_in[21];
    const float* gr_w   = (const float*)d_in[22];
    const float* gr_b   = (const float*)d_in[23];
    const float* gi_w   = (const float*)d_in[24];
    const float* gi_b   = (const float*)d_in[25];

    // workspace layout
    float* ws    = (float*)d_ws;
    float* n_rgb = ws;                    // 1179648
    float* n_ir  = n_rgb + 1179648;       // 1179648
    float* q_r   = n_ir  + 1179648;       // 294912
    float* kv_i  = q_r   + 294912;        // 589824
    float* q_i   = kv_i  + 589824;        // 294912
    float* kv_r  = q_i   + 294912;        // 589824
    float* a_rgb = kv_r  + 589824;        // 294912
    float* a_ir  = a_rgb + 294912;        // 294912  (tail = 4718592 floats)
    float* c_rgb = n_rgb;                 // reuse after attention partials consumed
    float* c_ir  = n_ir;

    // split-K depth chosen by available workspace (deterministic: ws_size fixed).
    // NS=6 partials (3981312 floats) placed after the live tensors if they fit;
    // else NS=3 partials (1990656 floats) overlap the dead n_rgb/n_ir region.
    const size_t tailOff = 4718592;
    const size_t ns6Bytes = (tailOff + (size_t)2 * 16 * 6 * 9 * kP) * sizeof(float);
    const bool useNS6 = ws_size >= ns6Bytes;
    float* part = useNS6 ? (ws + tailOff) : ws;

    float* out_rgb = (float*)d_out;
    float* out_ir  = out_rgb + (size_t)kB * kDim * kP;

    const dim3 blk(256);

    // 1) LN of both inputs (one launch)
    ln2_kernel<<<dim3(288, 2), blk, 0, stream>>>(f_rgb, nr_w, nr_b, n_rgb,
                                                 f_ir,  ni_w, ni_b, n_ir);
    // 2) all q/kv projections (one launch)
    qkv_conv<<<dim3(9, 24, 4), blk, 0, stream>>>(n_rgb, n_ir,
                                                 qr_w, qr_b, kvr_w, kvr_b,
                                                 qi_w, qi_b, kvi_w, kvi_b,
                                                 q_r, kv_r, q_i, kv_i);
    // 3) attention partials (split-K, both streams) + combine
    if (useNS6) {
        attn_part<6><<<dim3(9, 16, 12), blk, 0, stream>>>(q_r, kv_i, q_i, kv_r, part);
        attn_combine<6><<<dim3(9, 16, 2), blk, 0, stream>>>(part, a_rgb, a_ir);
    } else {
        attn_part<3><<<dim3(9, 16, 6), blk, 0, stream>>>(q_r, kv_i, q_i, kv_r, part);
        attn_combine<3><<<dim3(9, 16, 2), blk, 0, stream>>>(part, a_rgb, a_ir);
    }
    // 4) output projection (both streams) + LN (one launch)
    proj_conv<<<dim3(9, 32, 4), blk, 0, stream>>>(a_rgb, a_ir, pr_w, pr_b, pi_w, pi_b,
                                                  c_rgb, c_ir);
    ln2_kernel<<<dim3(288, 2), blk, 0, stream>>>(c_rgb, pr_lnw, pr_lnb, c_rgb,
                                                 c_ir,  pi_lnw, pi_lnb, c_ir);
    // 5) gate + residual (one launch)
    gate_conv<<<dim3(9, 32, 4), blk, 0, stream>>>(f_rgb, f_ir, c_rgb, c_ir,
                                                  gr_w, gr_b, gi_w, gi_b,
                                                  out_rgb, out_ir);
}

// Round 5
// 220.127 us; speedup vs baseline: 1.2314x; 1.2314x over previous
//
#include <hip/hip_runtime.h>

static constexpr int kDim   = 256;
static constexpr int kInner = 64;
static constexpr int kNH    = 8;
static constexpr int kHD    = 8;
static constexpr int kB     = 2;
static constexpr int kP     = 2304;   // 48*48
static constexpr float kScale = 0.35355339059327373f; // 8^-0.5
static constexpr float kEps   = 1e-6f;

// ---------------- LayerNorm over channels (C=256), both images in one launch.
// Block 256 = 16 positions x 16 channel-groups (16 ch each). grid (288, 2).
__global__ __launch_bounds__(256) void ln2_kernel(
    const float* __restrict__ x0, const float* __restrict__ w0,
    const float* __restrict__ b0, float* __restrict__ o0,
    const float* __restrict__ x1, const float* __restrict__ w1,
    const float* __restrict__ b1, float* __restrict__ o1)
{
    __shared__ float sb[16][16];
    __shared__ float ssb[16][16];
    const float* x = blockIdx.y ? x1 : x0;
    const float* w = blockIdx.y ? w1 : w0;
    const float* b = blockIdx.y ? b1 : b0;
    float*       o = blockIdx.y ? o1 : o0;
    const int pos = threadIdx.x & 15;
    const int grp = threadIdx.x >> 4;
    const int idx = blockIdx.x * 16 + pos;        // global (b,p) in 0..4607
    const int bb  = idx / kP;
    const int p   = idx - bb * kP;
    const size_t base = (size_t)bb * kDim * kP + p;
    const int c0 = grp * 16;

    float v[16];
    float s = 0.f, ss = 0.f;
    #pragma unroll
    for (int j = 0; j < 16; ++j) {
        v[j] = x[base + (size_t)(c0 + j) * kP];
        s += v[j]; ss += v[j] * v[j];
    }
    sb[grp][pos] = s; ssb[grp][pos] = ss;
    __syncthreads();
    float st = 0.f, sst = 0.f;
    #pragma unroll
    for (int g = 0; g < 16; ++g) { st += sb[g][pos]; sst += ssb[g][pos]; }
    const float mean = st * (1.f / kDim);
    const float rstd = rsqrtf(sst * (1.f / kDim) - mean * mean + kEps);
    #pragma unroll
    for (int j = 0; j < 16; ++j)
        o[base + (size_t)(c0 + j) * kP] = (v[j] - mean) * rstd * w[c0 + j] + b[c0 + j];
}

// ---------------- fused q/kv projections (C=256), 8 outputs (= one head) per thread.
// Outputs written position-major: [bh][P][8] (two contiguous float4 per thread).
// grid (9, 24, 4): y = tile (0..7 -> q head, 8..23 -> kv block), z = input*2 + batch.
__global__ __launch_bounds__(256) void qkv_conv(
    const float* __restrict__ n_rgb, const float* __restrict__ n_ir,
    const float* __restrict__ qr_w, const float* __restrict__ qr_b,
    const float* __restrict__ kvr_w, const float* __restrict__ kvr_b,
    const float* __restrict__ qi_w, const float* __restrict__ qi_b,
    const float* __restrict__ kvi_w, const float* __restrict__ kvi_b,
    float* __restrict__ q_r, float* __restrict__ k_r, float* __restrict__ v_r,
    float* __restrict__ q_i, float* __restrict__ k_i, float* __restrict__ v_i)
{
    const int inp  = blockIdx.z >> 1, bb = blockIdx.z & 1;
    const int tile = blockIdx.y;
    const float* in = inp ? n_ir : n_rgb;
    const float* w; const float* bias; float* out; int h;
    if (tile < 8) {                                   // q, head = tile
        w = inp ? qi_w : qr_w;  bias = inp ? qi_b : qr_b;
        out = inp ? q_i : q_r;  h = tile;
        w += (size_t)h * 8 * kDim; bias += h * 8;
    } else {                                          // kv block
        const int t = tile - 8;                       // 0..15 (0..7 = K, 8..15 = V)
        w = inp ? kvi_w : kvr_w; bias = inp ? kvi_b : kvr_b;
        w += (size_t)t * 8 * kDim; bias += t * 8;
        if (t < 8) { out = inp ? k_i : k_r; h = t; }
        else       { out = inp ? v_i : v_r; h = t - 8; }
    }
    const int p = blockIdx.x * 256 + threadIdx.x;
    const float* ip = in + (size_t)bb * kDim * kP + p;
    float acc[8];
    #pragma unroll
    for (int r = 0; r < 8; ++r) acc[r] = bias[r];
    #pragma unroll 2
    for (int c = 0; c < kDim; c += 4) {
        float v[4];
        #pragma unroll
        for (int j = 0; j < 4; ++j) v[j] = ip[(size_t)(c + j) * kP];
        #pragma unroll
        for (int r = 0; r < 8; ++r) {
            const float4 w4 = *(const float4*)(w + (size_t)r * kDim + c);
            const float* ww = (const float*)&w4;
            #pragma unroll
            for (int j = 0; j < 4; ++j) acc[r] = fmaf(ww[j], v[j], acc[r]);
        }
    }
    float* op = out + ((size_t)(bb * kNH + h) * kP + p) * 8;
    *(float4*)op       = make_float4(acc[0], acc[1], acc[2], acc[3]);
    *(float4*)(op + 4) = make_float4(acc[4], acc[5], acc[6], acc[7]);
}

// ---------------- attention, single-pass (no max-subtract: |scores| ~ 0.1),
// split-K x NS. K/V position-major -> contiguous wave-uniform scalar loads.
// grid (9, 16, 2*NS): z = stream*NS + chunk. Writes (sum, o[8]) partials.
template <int NS>
__global__ __launch_bounds__(256) void attn_part(
    const float* __restrict__ q0, const float* __restrict__ k0, const float* __restrict__ v0,
    const float* __restrict__ q1, const float* __restrict__ k1, const float* __restrict__ v1,
    float* __restrict__ part)      // [2*16*NS][9][2304]
{
    constexpr int CH = kP / NS;
    const int stream = blockIdx.z / NS, chunk = blockIdx.z % NS;
    const float* q = stream ? q1 : q0;
    const float* K = stream ? k1 : k0;
    const float* V = stream ? v1 : v0;
    const int bh = blockIdx.y;
    const int p  = blockIdx.x * 256 + threadIdx.x;

    const float* qp = q + ((size_t)bh * kP + p) * 8;
    const float4 ql = *(const float4*)qp;
    const float4 qh = *(const float4*)(qp + 4);
    float qv[8] = { ql.x * kScale, ql.y * kScale, ql.z * kScale, ql.w * kScale,
                    qh.x * kScale, qh.y * kScale, qh.z * kScale, qh.w * kScale };

    const float* Kc = K + ((size_t)bh * kP + chunk * CH) * 8;
    const float* Vc = V + ((size_t)bh * kP + chunk * CH) * 8;

    float sum = 0.f;
    float ov[8];
    #pragma unroll
    for (int d = 0; d < 8; ++d) ov[d] = 0.f;

    for (int m0 = 0; m0 < CH; m0 += 4) {
        float4 kk[8], vv[8];                 // 4 keys x 8 dims, contiguous 256B
        const float4* kp = (const float4*)(Kc + (size_t)m0 * 8);
        const float4* vp = (const float4*)(Vc + (size_t)m0 * 8);
        #pragma unroll
        for (int j = 0; j < 8; ++j) { kk[j] = kp[j]; vv[j] = vp[j]; }
        #pragma unroll
        for (int jj = 0; jj < 4; ++jj) {
            const float* kd = (const float*)&kk[2 * jj];
            float s = 0.f;
            #pragma unroll
            for (int d = 0; d < 8; ++d) s = fmaf(qv[d], kd[d], s);
            const float e = __expf(s);
            sum += e;
            const float* vd = (const float*)&vv[2 * jj];
            #pragma unroll
            for (int d = 0; d < 8; ++d) ov[d] = fmaf(e, vd[d], ov[d]);
        }
    }
    float* pp = part + (size_t)((stream * 16 + bh) * NS + chunk) * 9 * kP + p;
    pp[0] = sum;
    #pragma unroll
    for (int d = 0; d < 8; ++d) pp[(size_t)(1 + d) * kP] = ov[d];
}

// ---------------- combine split-K partials -> a_* in [b][64ch][P] layout.
// grid (9, 16, 2): z = stream.
template <int NS>
__global__ __launch_bounds__(256) void attn_combine(
    const float* __restrict__ part, float* __restrict__ a_rgb, float* __restrict__ a_ir)
{
    const int stream = blockIdx.z;
    const int bh = blockIdx.y;
    const int bb = bh >> 3, h = bh & 7;
    const int p  = blockIdx.x * 256 + threadIdx.x;
    float sum = 0.f;
    float ov[kHD];
    #pragma unroll
    for (int d = 0; d < kHD; ++d) ov[d] = 0.f;
    #pragma unroll
    for (int c = 0; c < NS; ++c) {
        const float* pp = part + (size_t)((stream * 16 + bh) * NS + c) * 9 * kP + p;
        sum += pp[0];
        #pragma unroll
        for (int d = 0; d < kHD; ++d) ov[d] += pp[(size_t)(1 + d) * kP];
    }
    const float inv = 1.f / sum;
    float* a = (stream ? a_ir : a_rgb) + ((size_t)bb * kInner + h * kHD) * kP + p;
    #pragma unroll
    for (int d = 0; d < kHD; ++d) a[(size_t)d * kP] = ov[d] * inv;
}

// ---------------- output projection (C=64 -> O=256), both streams.
// grid (9, 32, 4): z = stream*2 + batch.
__global__ __launch_bounds__(256) void proj_conv(
    const float* __restrict__ a_rgb, const float* __restrict__ a_ir,
    const float* __restrict__ pr_w, const float* __restrict__ pr_b,
    const float* __restrict__ pi_w, const float* __restrict__ pi_b,
    float* __restrict__ c_rgb, float* __restrict__ c_ir)
{
    const int stream = blockIdx.z >> 1, bb = blockIdx.z & 1;
    const int ot = blockIdx.y * 8;
    const float* in   = stream ? a_ir : a_rgb;
    const float* w    = stream ? pi_w : pr_w;
    const float* bias = stream ? pi_b : pr_b;
    float*       out  = stream ? c_ir : c_rgb;
    const int p = blockIdx.x * 256 + threadIdx.x;
    const float* ip = in + (size_t)bb * kInner * kP + p;
    float acc[8];
    #pragma unroll
    for (int r = 0; r < 8; ++r) acc[r] = bias[ot + r];
    #pragma unroll 2
    for (int c = 0; c < kInner; c += 4) {
        float v[4];
        #pragma unroll
        for (int j = 0; j < 4; ++j) v[j] = ip[(size_t)(c + j) * kP];
        #pragma unroll
        for (int r = 0; r < 8; ++r) {
            const float4 w4 = *(const float4*)(w + (size_t)(ot + r) * kInner + c);
            const float* ww = (const float*)&w4;
            #pragma unroll
            for (int j = 0; j < 4; ++j) acc[r] = fmaf(ww[j], v[j], acc[r]);
        }
    }
    float* op = out + ((size_t)bb * kDim + ot) * kP + p;
    #pragma unroll
    for (int r = 0; r < 8; ++r) op[(size_t)r * kP] = acc[r];
}

// ---------------- gate + residual (C=512 -> O=256), both streams.
// grid (9, 32, 4): z = stream*2 + batch.
__global__ __launch_bounds__(256) void gate_conv(
    const float* __restrict__ f_rgb, const float* __restrict__ f_ir,
    const float* __restrict__ c_rgb, const float* __restrict__ c_ir,
    const float* __restrict__ gr_w, const float* __restrict__ gr_b,
    const float* __restrict__ gi_w, const float* __restrict__ gi_b,
    float* __restrict__ out_rgb, float* __restrict__ out_ir)
{
    const int stream = blockIdx.z >> 1, bb = blockIdx.z & 1;
    const int ot = blockIdx.y * 8;
    const float* f    = stream ? f_ir  : f_rgb;
    const float* cr   = stream ? c_ir  : c_rgb;
    const float* w    = stream ? gi_w  : gr_w;
    const float* bias = stream ? gi_b  : gr_b;
    float*       out  = stream ? out_ir : out_rgb;
    const int p = blockIdx.x * 256 + threadIdx.x;
    const float* fb = f  + (size_t)bb * kDim * kP + p;
    const float* cb = cr + (size_t)bb * kDim * kP + p;
    float acc[8];
    #pragma unroll
    for (int r = 0; r < 8; ++r) acc[r] = bias[ot + r];
    #pragma unroll 2
    for (int c = 0; c < kDim; c += 4) {
        float v[4];
        #pragma unroll
        for (int j = 0; j < 4; ++j) v[j] = fb[(size_t)(c + j) * kP];
        #pragma unroll
        for (int r = 0; r < 8; ++r) {
            const float4 w4 = *(const float4*)(w + (size_t)(ot + r) * (2 * kDim) + c);
            const float* ww = (const float*)&w4;
            #pragma unroll
            for (int j = 0; j < 4; ++j) acc[r] = fmaf(ww[j], v[j], acc[r]);
        }
    }
    #pragma unroll 2
    for (int c = 0; c < kDim; c += 4) {
        float v[4];
        #pragma unroll
        for (int j = 0; j < 4; ++j) v[j] = cb[(size_t)(c + j) * kP];
        #pragma unroll
        for (int r = 0; r < 8; ++r) {
            const float4 w4 = *(const float4*)(w + (size_t)(ot + r) * (2 * kDim) + kDim + c);
            const float* ww = (const float*)&w4;
            #pragma unroll
            for (int j = 0; j < 4; ++j) acc[r] = fmaf(ww[j], v[j], acc[r]);
        }
    }
    float* op = out + ((size_t)bb * kDim + ot) * kP + p;
    #pragma unroll
    for (int r = 0; r < 8; ++r) {
        const float g = 1.f / (1.f + __expf(-acc[r]));
        op[(size_t)r * kP] = fb[(size_t)(ot + r) * kP] + g * cb[(size_t)(ot + r) * kP];
    }
}

extern "C" void kernel_launch(void* const* d_in, const int* in_sizes, int n_in,
                              void* d_out, int out_size, void* d_ws, size_t ws_size,
                              hipStream_t stream)
{
    const float* f_rgb  = (const float*)d_in[0];
    const float* f_ir   = (const float*)d_in[1];
    const float* nr_w   = (const float*)d_in[2];
    const float* nr_b   = (const float*)d_in[3];
    const float* ni_w   = (const float*)d_in[4];
    const float* ni_b   = (const float*)d_in[5];
    const float* qr_w   = (const float*)d_in[6];
    const float* qr_b   = (const float*)d_in[7];
    const float* kvi_w  = (const float*)d_in[8];
    const float* kvi_b  = (const float*)d_in[9];
    const float* qi_w   = (const float*)d_in[10];
    const float* qi_b   = (const float*)d_in[11];
    const float* kvr_w  = (const float*)d_in[12];
    const float* kvr_b  = (const float*)d_in[13];
    const float* pr_w   = (const float*)d_in[14];
    const float* pr_b   = (const float*)d_in[15];
    const float* pr_lnw = (const float*)d_in[16];
    const float* pr_lnb = (const float*)d_in[17];
    const float* pi_w   = (const float*)d_in[18];
    const float* pi_b   = (const float*)d_in[19];
    const float* pi_lnw = (const float*)d_in[20];
    const float* pi_lnb = (const float*)d_in[21];
    const float* gr_w   = (const float*)d_in[22];
    const float* gr_b   = (const float*)d_in[23];
    const float* gi_w   = (const float*)d_in[24];
    const float* gi_b   = (const float*)d_in[25];

    // workspace layout (floats)
    float* ws    = (float*)d_ws;
    float* n_rgb = ws;                    // 1179648
    float* n_ir  = n_rgb + 1179648;       // 1179648
    float* q_r   = n_ir  + 1179648;       // 294912 each below
    float* q_i   = q_r   + 294912;
    float* k_r   = q_i   + 294912;
    float* v_r   = k_r   + 294912;
    float* k_i   = v_r   + 294912;
    float* v_i   = k_i   + 294912;
    float* a_rgb = v_i   + 294912;
    float* a_ir  = a_rgb + 294912;        // tail = 4718592 floats
    float* c_rgb = n_rgb;                 // reuse after attention partials consumed
    float* c_ir  = n_ir;

    // split-K depth chosen by available workspace (deterministic: ws_size fixed).
    const size_t tailOff = 4718592;
    const size_t ns6Bytes = (tailOff + (size_t)2 * 16 * 6 * 9 * kP) * sizeof(float);
    const bool useNS6 = ws_size >= ns6Bytes;
    float* part = useNS6 ? (ws + tailOff) : ws;

    float* out_rgb = (float*)d_out;
    float* out_ir  = out_rgb + (size_t)kB * kDim * kP;

    const dim3 blk(256);

    // 1) LN of both inputs (one launch)
    ln2_kernel<<<dim3(288, 2), blk, 0, stream>>>(f_rgb, nr_w, nr_b, n_rgb,
                                                 f_ir,  ni_w, ni_b, n_ir);
    // 2) all q/kv projections (one launch), position-major outputs
    qkv_conv<<<dim3(9, 24, 4), blk, 0, stream>>>(n_rgb, n_ir,
                                                 qr_w, qr_b, kvr_w, kvr_b,
                                                 qi_w, qi_b, kvi_w, kvi_b,
                                                 q_r, k_r, v_r, q_i, k_i, v_i);
    // 3) attention partials (split-K, both streams) + combine
    if (useNS6) {
        attn_part<6><<<dim3(9, 16, 12), blk, 0, stream>>>(q_r, k_i, v_i, q_i, k_r, v_r, part);
        attn_combine<6><<<dim3(9, 16, 2), blk, 0, stream>>>(part, a_rgb, a_ir);
    } else {
        attn_part<3><<<dim3(9, 16, 6), blk, 0, stream>>>(q_r, k_i, v_i, q_i, k_r, v_r, part);
        attn_combine<3><<<dim3(9, 16, 2), blk, 0, stream>>>(part, a_rgb, a_ir);
    }
    // 4) output projection (both streams) + LN (one launch)
    proj_conv<<<dim3(9, 32, 4), blk, 0, stream>>>(a_rgb, a_ir, pr_w, pr_b, pi_w, pi_b,
                                                  c_rgb, c_ir);
    ln2_kernel<<<dim3(288, 2), blk, 0, stream>>>(c_rgb, pr_lnw, pr_lnb, c_rgb,
                                                 c_ir,  pi_lnw, pi_lnb, c_ir);
    // 5) gate + residual (one launch)
    gate_conv<<<dim3(9, 32, 4), blk, 0, stream>>>(f_rgb, f_ir, c_rgb, c_ir,
                                                  gr_w, gr_b, gi_w, gi_b,
                                                  out_rgb, out_ir);
}

// Round 6
// 165.826 us; speedup vs baseline: 1.6346x; 1.3275x over previous
//
#include <hip/hip_runtime.h>

static constexpr int kDim   = 256;
static constexpr int kInner = 64;
static constexpr int kNH    = 8;
static constexpr int kHD    = 8;
static constexpr int kB     = 2;
static constexpr int kP     = 2304;   // 48*48
static constexpr float kScale = 0.35355339059327373f; // 8^-0.5
static constexpr float kEps   = 1e-6f;

typedef _Float16 half4f __attribute__((ext_vector_type(4)));
typedef float    f32x4  __attribute__((ext_vector_type(4)));

// ---------------- LayerNorm over channels (C=256), both images in one launch.
__global__ __launch_bounds__(256) void ln2_kernel(
    const float* __restrict__ x0, const float* __restrict__ w0,
    const float* __restrict__ b0, float* __restrict__ o0,
    const float* __restrict__ x1, const float* __restrict__ w1,
    const float* __restrict__ b1, float* __restrict__ o1)
{
    __shared__ float sb[16][16];
    __shared__ float ssb[16][16];
    const float* x = blockIdx.y ? x1 : x0;
    const float* w = blockIdx.y ? w1 : w0;
    const float* b = blockIdx.y ? b1 : b0;
    float*       o = blockIdx.y ? o1 : o0;
    const int pos = threadIdx.x & 15;
    const int grp = threadIdx.x >> 4;
    const int idx = blockIdx.x * 16 + pos;
    const int bb  = idx / kP;
    const int p   = idx - bb * kP;
    const size_t base = (size_t)bb * kDim * kP + p;
    const int c0 = grp * 16;

    float v[16];
    float s = 0.f, ss = 0.f;
    #pragma unroll
    for (int j = 0; j < 16; ++j) {
        v[j] = x[base + (size_t)(c0 + j) * kP];
        s += v[j]; ss += v[j] * v[j];
    }
    sb[grp][pos] = s; ssb[grp][pos] = ss;
    __syncthreads();
    float st = 0.f, sst = 0.f;
    #pragma unroll
    for (int g = 0; g < 16; ++g) { st += sb[g][pos]; sst += ssb[g][pos]; }
    const float mean = st * (1.f / kDim);
    const float rstd = rsqrtf(sst * (1.f / kDim) - mean * mean + kEps);
    #pragma unroll
    for (int j = 0; j < 16; ++j)
        o[base + (size_t)(c0 + j) * kP] = (v[j] - mean) * rstd * w[c0 + j] + b[c0 + j];
}

// ---------------- fused q/kv projections (C=256) -> f16 outputs for MFMA attn.
// Q: [bh][P][8] f16, pre-scaled by kScale. K: [bh][P][8] f16. V: transposed [bh][8][P] f16.
// grid (9, 24, 4): y = tile (0..7 q head, 8..15 K head, 16..23 V head), z = input*2 + batch.
__global__ __launch_bounds__(256) void qkv_conv(
    const float* __restrict__ n_rgb, const float* __restrict__ n_ir,
    const float* __restrict__ qr_w, const float* __restrict__ qr_b,
    const float* __restrict__ kvr_w, const float* __restrict__ kvr_b,
    const float* __restrict__ qi_w, const float* __restrict__ qi_b,
    const float* __restrict__ kvi_w, const float* __restrict__ kvi_b,
    _Float16* __restrict__ q_r, _Float16* __restrict__ k_r, _Float16* __restrict__ vt_r,
    _Float16* __restrict__ q_i, _Float16* __restrict__ k_i, _Float16* __restrict__ vt_i)
{
    const int inp  = blockIdx.z >> 1, bb = blockIdx.z & 1;
    const int tile = blockIdx.y;
    const float* in = inp ? n_ir : n_rgb;
    const float* w; const float* bias;
    if (tile < 8) { w = inp ? qi_w : qr_w;   bias = inp ? qi_b : qr_b;
                    w += (size_t)tile * 8 * kDim; bias += tile * 8; }
    else          { const int t = tile - 8;
                    w = inp ? kvi_w : kvr_w; bias = inp ? kvi_b : kvr_b;
                    w += (size_t)t * 8 * kDim; bias += t * 8; }
    const int p = blockIdx.x * 256 + threadIdx.x;
    const float* ip = in + (size_t)bb * kDim * kP + p;
    float acc[8];
    #pragma unroll
    for (int r = 0; r < 8; ++r) acc[r] = bias[r];
    #pragma unroll 2
    for (int c = 0; c < kDim; c += 4) {
        float v[4];
        #pragma unroll
        for (int j = 0; j < 4; ++j) v[j] = ip[(size_t)(c + j) * kP];
        #pragma unroll
        for (int r = 0; r < 8; ++r) {
            const float4 w4 = *(const float4*)(w + (size_t)r * kDim + c);
            const float* ww = (const float*)&w4;
            #pragma unroll
            for (int j = 0; j < 4; ++j) acc[r] = fmaf(ww[j], v[j], acc[r]);
        }
    }
    if (tile < 8) {                       // Q (scaled), pos-major
        _Float16* qp = (inp ? q_i : q_r) + ((size_t)(bb * kNH + tile) * kP + p) * 8;
        half4f lo = { (_Float16)(acc[0]*kScale), (_Float16)(acc[1]*kScale),
                      (_Float16)(acc[2]*kScale), (_Float16)(acc[3]*kScale) };
        half4f hi = { (_Float16)(acc[4]*kScale), (_Float16)(acc[5]*kScale),
                      (_Float16)(acc[6]*kScale), (_Float16)(acc[7]*kScale) };
        *(half4f*)qp = lo; *(half4f*)(qp + 4) = hi;
    } else if (tile < 16) {               // K, pos-major
        const int h = tile - 8;
        _Float16* kp = (inp ? k_i : k_r) + ((size_t)(bb * kNH + h) * kP + p) * 8;
        half4f lo = { (_Float16)acc[0], (_Float16)acc[1], (_Float16)acc[2], (_Float16)acc[3] };
        half4f hi = { (_Float16)acc[4], (_Float16)acc[5], (_Float16)acc[6], (_Float16)acc[7] };
        *(half4f*)kp = lo; *(half4f*)(kp + 4) = hi;
    } else {                              // V, transposed [bh][8][P]
        const int h = tile - 16;
        _Float16* vp = (inp ? vt_i : vt_r) + (size_t)(bb * kNH + h) * 8 * kP + p;
        #pragma unroll
        for (int d = 0; d < 8; ++d) vp[(size_t)d * kP] = (_Float16)acc[d];
    }
}

// ---------------- fused MFMA flash attention (both streams).
// grid (36, 16, 2): x = q-tile of 64, y = bh, z = stream. block 256 = 4 waves x 16 q.
// S^T = mfma(K, Q^T); exp in regs; out^T = mfma(V^T, P^T) -- C layout of S^T IS the
// B-frag layout of P^T for 16x16x16, so no cross-lane traffic in softmax.
__global__ __launch_bounds__(256) void attn_mfma(
    const _Float16* __restrict__ q0, const _Float16* __restrict__ k0, const _Float16* __restrict__ vt0,
    const _Float16* __restrict__ q1, const _Float16* __restrict__ k1, const _Float16* __restrict__ vt1,
    float* __restrict__ a0, float* __restrict__ a1)
{
    __shared__ _Float16 Ksm[256 * 24];   // 48B rows: halfs 0..7 = K[d], 8..15 = zeros
    __shared__ _Float16 Vsm[16 * 264];   // rows d (8 real + 8 zero), 264-half pitch
    const _Float16* Qg = blockIdx.z ? q1  : q0;
    const _Float16* Kg = blockIdx.z ? k1  : k0;
    const _Float16* Vg = blockIdx.z ? vt1 : vt0;
    float*          Ag = blockIdx.z ? a1  : a0;
    const int bh = blockIdx.y;
    const int bb = bh >> 3, h = bh & 7;
    const int tid  = threadIdx.x;
    const int wv   = tid >> 6;
    const int lane = tid & 63;
    const int r16  = lane & 15;
    const int g    = lane >> 4;

    // zero pad regions (never overwritten by staging)
    {
        const float4 z4 = make_float4(0.f, 0.f, 0.f, 0.f);
        *(float4*)(Ksm + tid * 24 + 8) = z4;           // halfs 8..15 of row tid
        for (int i = tid; i < 264; i += 256)
            *(float4*)(Vsm + 8 * 264 + i * 8) = z4;    // rows 8..15
    }

    // persistent Q fragment: B[d=4g+j][q=r16]
    const int qg = blockIdx.x * 64 + wv * 16 + r16;
    half4f qf = (half4f){0, 0, 0, 0};
    if (g < 2) qf = *(const half4f*)(Qg + ((size_t)bh * kP + qg) * 8 + g * 4);

    f32x4 of = (f32x4){0.f, 0.f, 0.f, 0.f};
    float rs = 0.f;

    for (int ch = 0; ch < 9; ++ch) {
        if (ch) __syncthreads();
        const int p0 = ch * 256;
        // stage K chunk: key tid -> row tid (16B)
        *(float4*)(Ksm + tid * 24) = *(const float4*)(Kg + ((size_t)bh * kP + p0 + tid) * 8);
        // stage V^T chunk: 8 rows x 256 cols
        {
            const int d = tid >> 5, c8 = (tid & 31) * 8;
            *(float4*)(Vsm + d * 264 + c8) =
                *(const float4*)(Vg + ((size_t)(bh * 8 + d)) * kP + p0 + c8);
        }
        __syncthreads();
        #pragma unroll
        for (int kt = 0; kt < 16; ++kt) {
            // A = K-tile: row=key=r16, k-dim d=4g+j (zeros for g>=2)
            const half4f kf = *(const half4f*)(Ksm + (kt * 16 + r16) * 24 + g * 4);
            f32x4 s = __builtin_amdgcn_mfma_f32_16x16x16f16(kf, qf, (f32x4){0.f,0.f,0.f,0.f}, 0, 0, 0);
            const float e0 = __expf(s[0]), e1 = __expf(s[1]);
            const float e2 = __expf(s[2]), e3 = __expf(s[3]);
            rs += (e0 + e1) + (e2 + e3);
            const half4f pf = { (_Float16)e0, (_Float16)e1, (_Float16)e2, (_Float16)e3 };
            // A = V^T-tile: row=d=r16 (zeros for d>=8), k=4g+j
            const half4f vf = *(const half4f*)(Vsm + r16 * 264 + kt * 16 + g * 4);
            of = __builtin_amdgcn_mfma_f32_16x16x16f16(vf, pf, of, 0, 0, 0);
        }
    }
    // total rowsum for q=r16: reduce over the 4 lane-groups
    rs += __shfl_xor(rs, 16, 64);
    rs += __shfl_xor(rs, 32, 64);
    const float inv = 1.f / rs;
    if (g < 2) {   // rows d = 4g+i < 8 hold real output
        float* op = Ag + ((size_t)(bb * kInner + h * 8 + g * 4)) * kP + qg;
        #pragma unroll
        for (int i = 0; i < 4; ++i) op[(size_t)i * kP] = of[i] * inv;
    }
}

// ---------------- output projection (C=64 -> O=256), both streams.
__global__ __launch_bounds__(256) void proj_conv(
    const float* __restrict__ a_rgb, const float* __restrict__ a_ir,
    const float* __restrict__ pr_w, const float* __restrict__ pr_b,
    const float* __restrict__ pi_w, const float* __restrict__ pi_b,
    float* __restrict__ c_rgb, float* __restrict__ c_ir)
{
    const int stream = blockIdx.z >> 1, bb = blockIdx.z & 1;
    const int ot = blockIdx.y * 8;
    const float* in   = stream ? a_ir : a_rgb;
    const float* w    = stream ? pi_w : pr_w;
    const float* bias = stream ? pi_b : pr_b;
    float*       out  = stream ? c_ir : c_rgb;
    const int p = blockIdx.x * 256 + threadIdx.x;
    const float* ip = in + (size_t)bb * kInner * kP + p;
    float acc[8];
    #pragma unroll
    for (int r = 0; r < 8; ++r) acc[r] = bias[ot + r];
    #pragma unroll 2
    for (int c = 0; c < kInner; c += 4) {
        float v[4];
        #pragma unroll
        for (int j = 0; j < 4; ++j) v[j] = ip[(size_t)(c + j) * kP];
        #pragma unroll
        for (int r = 0; r < 8; ++r) {
            const float4 w4 = *(const float4*)(w + (size_t)(ot + r) * kInner + c);
            const float* ww = (const float*)&w4;
            #pragma unroll
            for (int j = 0; j < 4; ++j) acc[r] = fmaf(ww[j], v[j], acc[r]);
        }
    }
    float* op = out + ((size_t)bb * kDim + ot) * kP + p;
    #pragma unroll
    for (int r = 0; r < 8; ++r) op[(size_t)r * kP] = acc[r];
}

// ---------------- gate + residual (C=512 -> O=256), both streams.
__global__ __launch_bounds__(256) void gate_conv(
    const float* __restrict__ f_rgb, const float* __restrict__ f_ir,
    const float* __restrict__ c_rgb, const float* __restrict__ c_ir,
    const float* __restrict__ gr_w, const float* __restrict__ gr_b,
    const float* __restrict__ gi_w, const float* __restrict__ gi_b,
    float* __restrict__ out_rgb, float* __restrict__ out_ir)
{
    const int stream = blockIdx.z >> 1, bb = blockIdx.z & 1;
    const int ot = blockIdx.y * 8;
    const float* f    = stream ? f_ir  : f_rgb;
    const float* cr   = stream ? c_ir  : c_rgb;
    const float* w    = stream ? gi_w  : gr_w;
    const float* bias = stream ? gi_b  : gr_b;
    float*       out  = stream ? out_ir : out_rgb;
    const int p = blockIdx.x * 256 + threadIdx.x;
    const float* fb = f  + (size_t)bb * kDim * kP + p;
    const float* cb = cr + (size_t)bb * kDim * kP + p;
    float acc[8];
    #pragma unroll
    for (int r = 0; r < 8; ++r) acc[r] = bias[ot + r];
    #pragma unroll 2
    for (int c = 0; c < kDim; c += 4) {
        float v[4];
        #pragma unroll
        for (int j = 0; j < 4; ++j) v[j] = fb[(size_t)(c + j) * kP];
        #pragma unroll
        for (int r = 0; r < 8; ++r) {
            const float4 w4 = *(const float4*)(w + (size_t)(ot + r) * (2 * kDim) + c);
            const float* ww = (const float*)&w4;
            #pragma unroll
            for (int j = 0; j < 4; ++j) acc[r] = fmaf(ww[j], v[j], acc[r]);
        }
    }
    #pragma unroll 2
    for (int c = 0; c < kDim; c += 4) {
        float v[4];
        #pragma unroll
        for (int j = 0; j < 4; ++j) v[j] = cb[(size_t)(c + j) * kP];
        #pragma unroll
        for (int r = 0; r < 8; ++r) {
            const float4 w4 = *(const float4*)(w + (size_t)(ot + r) * (2 * kDim) + kDim + c);
            const float* ww = (const float*)&w4;
            #pragma unroll
            for (int j = 0; j < 4; ++j) acc[r] = fmaf(ww[j], v[j], acc[r]);
        }
    }
    float* op = out + ((size_t)bb * kDim + ot) * kP + p;
    #pragma unroll
    for (int r = 0; r < 8; ++r) {
        const float gt = 1.f / (1.f + __expf(-acc[r]));
        op[(size_t)r * kP] = fb[(size_t)(ot + r) * kP] + gt * cb[(size_t)(ot + r) * kP];
    }
}

extern "C" void kernel_launch(void* const* d_in, const int* in_sizes, int n_in,
                              void* d_out, int out_size, void* d_ws, size_t ws_size,
                              hipStream_t stream)
{
    const float* f_rgb  = (const float*)d_in[0];
    const float* f_ir   = (const float*)d_in[1];
    const float* nr_w   = (const float*)d_in[2];
    const float* nr_b   = (const float*)d_in[3];
    const float* ni_w   = (const float*)d_in[4];
    const float* ni_b   = (const float*)d_in[5];
    const float* qr_w   = (const float*)d_in[6];
    const float* qr_b   = (const float*)d_in[7];
    const float* kvi_w  = (const float*)d_in[8];
    const float* kvi_b  = (const float*)d_in[9];
    const float* qi_w   = (const float*)d_in[10];
    const float* qi_b   = (const float*)d_in[11];
    const float* kvr_w  = (const float*)d_in[12];
    const float* kvr_b  = (const float*)d_in[13];
    const float* pr_w   = (const float*)d_in[14];
    const float* pr_b   = (const float*)d_in[15];
    const float* pr_lnw = (const float*)d_in[16];
    const float* pr_lnb = (const float*)d_in[17];
    const float* pi_w   = (const float*)d_in[18];
    const float* pi_b   = (const float*)d_in[19];
    const float* pi_lnw = (const float*)d_in[20];
    const float* pi_lnb = (const float*)d_in[21];
    const float* gr_w   = (const float*)d_in[22];
    const float* gr_b   = (const float*)d_in[23];
    const float* gi_w   = (const float*)d_in[24];
    const float* gi_b   = (const float*)d_in[25];

    // workspace layout (floats)
    float* ws    = (float*)d_ws;
    float* n_rgb = ws;                        // 1179648
    float* n_ir  = n_rgb + 1179648;           // 1179648
    float* fp16base = n_ir + 1179648;         // 6 x 147456 floats (f16 arrays)
    _Float16* q_r  = (_Float16*)(fp16base);
    _Float16* k_r  = (_Float16*)(fp16base + 1 * 147456);
    _Float16* vt_r = (_Float16*)(fp16base + 2 * 147456);
    _Float16* q_i  = (_Float16*)(fp16base + 3 * 147456);
    _Float16* k_i  = (_Float16*)(fp16base + 4 * 147456);
    _Float16* vt_i = (_Float16*)(fp16base + 5 * 147456);
    float* a_rgb = fp16base + 6 * 147456;     // 294912
    float* a_ir  = a_rgb + 294912;            // 294912
    float* c_rgb = n_rgb;                     // reuse after projections
    float* c_ir  = n_ir;

    float* out_rgb = (float*)d_out;
    float* out_ir  = out_rgb + (size_t)kB * kDim * kP;

    const dim3 blk(256);

    // 1) LN of both inputs (one launch)
    ln2_kernel<<<dim3(288, 2), blk, 0, stream>>>(f_rgb, nr_w, nr_b, n_rgb,
                                                 f_ir,  ni_w, ni_b, n_ir);
    // 2) all q/kv projections (one launch), f16 outputs
    qkv_conv<<<dim3(9, 24, 4), blk, 0, stream>>>(n_rgb, n_ir,
                                                 qr_w, qr_b, kvr_w, kvr_b,
                                                 qi_w, qi_b, kvi_w, kvi_b,
                                                 q_r, k_r, vt_r, q_i, k_i, vt_i);
    // 3) fused MFMA attention (both streams, one launch)
    attn_mfma<<<dim3(36, 16, 2), blk, 0, stream>>>(q_r, k_i, vt_i, q_i, k_r, vt_r,
                                                   a_rgb, a_ir);
    // 4) output projection + LN
    proj_conv<<<dim3(9, 32, 4), blk, 0, stream>>>(a_rgb, a_ir, pr_w, pr_b, pi_w, pi_b,
                                                  c_rgb, c_ir);
    ln2_kernel<<<dim3(288, 2), blk, 0, stream>>>(c_rgb, pr_lnw, pr_lnb, c_rgb,
                                                 c_ir,  pi_lnw, pi_lnb, c_ir);
    // 5) gate + residual
    gate_conv<<<dim3(9, 32, 4), blk, 0, stream>>>(f_rgb, f_ir, c_rgb, c_ir,
                                                  gr_w, gr_b, gi_w, gi_b,
                                                  out_rgb, out_ir);
}